// Round 5
// baseline (227.028 us; speedup 1.0000x reference)
//
#include <hip/hip_runtime.h>
#include <hip/hip_bf16.h>

#define IN_F  4096
#define OUT_F 4096
#define NTOK  4096
#define RANK  32
#define GS    64
#define NG    64
#define KTOT  4224          // 66 groups * 64; group 64 = low-rank, group 65 = scale-0 dummy
#define NKT   66
#define ITERS 33
#define KCH   1024

typedef __attribute__((ext_vector_type(4))) float f32x4;
typedef __attribute__((ext_vector_type(8))) short bf16x8;
typedef __attribute__((ext_vector_type(4))) int   i32x4;

__device__ __forceinline__ ushort f2bf(float f) {
  union { float f; uint u; } c; c.f = f;
  const uint u = c.u;
  return (ushort)((u + 0x7fffu + ((u >> 16) & 1u)) >> 16);  // RNE
}
__device__ __forceinline__ uint pack4(int a, int b, int c, int d) {
  return (uint)(a & 255) | ((uint)(b & 255) << 8) | ((uint)(c & 255) << 16) | ((uint)(d & 255) << 24);
}

// ---------------------------------------------------------------------------
// Kernel 1: per-group int8 quant of x -> Aq[:,0:4096] int8 + AsclT[0:64][row].
// 16-lane group = one 64-elem quant group (4 floats/lane).
// ---------------------------------------------------------------------------
__global__ __launch_bounds__(256)
void quant_kernel(const float* __restrict__ x, char* __restrict__ Aq,
                  float* __restrict__ AsclT)
{
  const int tid  = threadIdx.x;
  const int wave = tid >> 6, lane = tid & 63;
  const int sub  = lane & 15;
  const int ggrp = blockIdx.x * 16 + wave * 4 + (lane >> 4);
  const int row  = ggrp >> 6, g = ggrp & 63;

  const float4 v = *(const float4*)(x + (size_t)row * IN_F + g * GS + sub * 4);
  float m = fmaxf(fmaxf(fabsf(v.x), fabsf(v.y)), fmaxf(fabsf(v.z), fabsf(v.w)));
  m = fmaxf(m, __shfl_xor(m, 1));
  m = fmaxf(m, __shfl_xor(m, 2));
  m = fmaxf(m, __shfl_xor(m, 4));
  m = fmaxf(m, __shfl_xor(m, 8));
  const float as  = (m > 0.f) ? m * (1.f / 127.f) : 1.f;
  const float inv = (m > 0.f) ? 127.f / m : 1.f;

  const int q0 = (int)fminf(fmaxf(rintf(v.x * inv), -127.f), 127.f);
  const int q1 = (int)fminf(fmaxf(rintf(v.y * inv), -127.f), 127.f);
  const int q2 = (int)fminf(fmaxf(rintf(v.z * inv), -127.f), 127.f);
  const int q3 = (int)fminf(fmaxf(rintf(v.w * inv), -127.f), 127.f);

  *(uint*)(Aq + (size_t)row * KTOT + g * GS + sub * 4) = pack4(q0, q1, q2, q3);
  if (sub == 0) AsclT[(size_t)g * NTOK + row] = as;
}

// ---------------------------------------------------------------------------
// Kernel 2: pack int4 weights (int32) -> Bq int8; transpose wscale -> BsclT.
// One block per output row o.
// ---------------------------------------------------------------------------
__global__ __launch_bounds__(256)
void wpack_kernel(const int* __restrict__ qw, const float* __restrict__ wsc,
                  char* __restrict__ Bq, float* __restrict__ BsclT)
{
  const int o = blockIdx.x, t = threadIdx.x;
  const int4 a = *(const int4*)(qw + (size_t)o * IN_F + t * 16);
  const int4 b = *(const int4*)(qw + (size_t)o * IN_F + t * 16 + 4);
  const int4 c = *(const int4*)(qw + (size_t)o * IN_F + t * 16 + 8);
  const int4 d = *(const int4*)(qw + (size_t)o * IN_F + t * 16 + 12);
  uint4 st;
  st.x = pack4(a.x, a.y, a.z, a.w);
  st.y = pack4(b.x, b.y, b.z, b.w);
  st.z = pack4(c.x, c.y, c.z, c.w);
  st.w = pack4(d.x, d.y, d.z, d.w);
  *(uint4*)(Bq + (size_t)o * KTOT + t * 16) = st;
  if (t < NG) BsclT[(size_t)t * OUT_F + o] = wsc[o * NG + t];
}

// ---------------------------------------------------------------------------
// Kernel 3: pd -> pdT bf16 (for the lr MFMA).
// ---------------------------------------------------------------------------
__global__ __launch_bounds__(256)
void pdt_kernel(const float* __restrict__ pd, ushort* __restrict__ pdT)
{
  const int id = blockIdx.x * 256 + threadIdx.x;   // 0..4095
  #pragma unroll
  for (int r = 0; r < RANK; ++r)
    pdT[(size_t)r * IN_F + id] = f2bf(pd[(size_t)id * RANK + r]);
}

// ---------------------------------------------------------------------------
// Kernel 4: lr partials = x @ pdT^T via bf16 MFMA (RAW x, cvt-staged to LDS).
// Grid 256 = 64 M-tiles x 4 K-chunks.
// ---------------------------------------------------------------------------
__global__ __launch_bounds__(256)
void lrx_kernel(const float* __restrict__ x, const ushort* __restrict__ pdT,
                float* __restrict__ part)
{
  __shared__ alignas(16) ushort lA[64 * 64];   // 8 KB bf16, XOR-swizzled
  const int tid  = threadIdx.x;
  const int wave = tid >> 6, lane = tid & 63;
  const int mt = blockIdx.x >> 2;
  const int kc = blockIdx.x & 3;
  const int k0 = kc * KCH;

  f32x4 acc[2];
  #pragma unroll
  for (int n = 0; n < 2; ++n) acc[n] = f32x4{0.f, 0.f, 0.f, 0.f};

  for (int kt = 0; kt < KCH / 64; ++kt) {
    __syncthreads();
    #pragma unroll
    for (int s = 0; s < 4; ++s) {
      const int row = (tid >> 4) + s * 16;
      const int c4  = tid & 15;
      const float4 v = *(const float4*)(x + (size_t)(mt * 64 + row) * IN_F + k0 + kt * 64 + c4 * 4);
      uint2 p;
      p.x = (uint)f2bf(v.x) | ((uint)f2bf(v.y) << 16);
      p.y = (uint)f2bf(v.z) | ((uint)f2bf(v.w) << 16);
      const int addr = (row * 128 + c4 * 8) ^ ((row & 7) << 4);
      *(uint2*)((char*)lA + addr) = p;
    }
    __syncthreads();
    #pragma unroll
    for (int ks = 0; ks < 2; ++ks) {
      const int kb  = (ks * 32 + (lane >> 4) * 8) * 2;
      const int row = wave * 16 + (lane & 15);
      const int addr = (row * 128 + kb) ^ ((row & 7) << 4);
      bf16x8 af = *(const bf16x8*)((const char*)lA + addr);
      #pragma unroll
      for (int n = 0; n < 2; ++n) {
        const int prow = n * 16 + (lane & 15);
        bf16x8 bf = *(const bf16x8*)(pdT + (size_t)prow * IN_F + k0 + kt * 64 + ks * 32 + (lane >> 4) * 8);
        acc[n] = __builtin_amdgcn_mfma_f32_16x16x32_bf16(af, bf, acc[n], 0, 0, 0);
      }
    }
  }
  const int r0   = lane & 15;
  const int rowb = mt * 64 + wave * 16 + (lane >> 4) * 4;
  #pragma unroll
  for (int n = 0; n < 2; ++n)
    #pragma unroll
    for (int i = 0; i < 4; ++i)
      part[((size_t)kc * 4096 + rowb + i) * 32 + n * 16 + r0] = acc[n][i];
}

// ---------------------------------------------------------------------------
// Kernel 5: combine lr partials, int8-quantize per row -> Aq group 64;
// AsclT[64][row] = scale, AsclT[65][row] = 0.
// ---------------------------------------------------------------------------
__global__ __launch_bounds__(256)
void lrq_kernel(const float* __restrict__ part, char* __restrict__ Aq,
                float* __restrict__ AsclT)
{
  const int id  = blockIdx.x * 256 + threadIdx.x;  // 131072
  const int row = id >> 5, r = id & 31;
  const float s = part[(size_t)row * 32 + r]
                + part[(size_t)(4096 + row) * 32 + r]
                + part[(size_t)(8192 + row) * 32 + r]
                + part[(size_t)(12288 + row) * 32 + r];
  float m = fabsf(s);
  m = fmaxf(m, __shfl_xor(m, 1));
  m = fmaxf(m, __shfl_xor(m, 2));
  m = fmaxf(m, __shfl_xor(m, 4));
  m = fmaxf(m, __shfl_xor(m, 8));
  m = fmaxf(m, __shfl_xor(m, 16));
  const float as  = (m > 0.f) ? m * (1.f / 127.f) : 1.f;
  const float inv = (m > 0.f) ? 127.f / m : 1.f;
  const int q = (int)fminf(fmaxf(rintf(s * inv), -127.f), 127.f);
  char* dst = Aq + (size_t)row * KTOT + IN_F;
  dst[r]        = (char)q;
  dst[RANK + r] = 0;
  if (r == 0) {
    AsclT[(size_t)64 * NTOK + row] = as;
    AsclT[(size_t)65 * NTOK + row] = 0.f;
  }
}

// ---------------------------------------------------------------------------
// Kernel 6: pu -> int8 per-column quant -> Bq group 64; BsclT[64], BsclT[65]=0.
// ---------------------------------------------------------------------------
__global__ __launch_bounds__(256)
void puq_kernel(const float* __restrict__ pu, char* __restrict__ Bq,
                float* __restrict__ BsclT)
{
  const int o = blockIdx.x * 256 + threadIdx.x;
  float v[RANK]; float m = 0.f;
  #pragma unroll
  for (int r = 0; r < RANK; ++r) {
    v[r] = pu[(size_t)r * OUT_F + o];
    m = fmaxf(m, fabsf(v[r]));
  }
  const float ws  = (m > 0.f) ? m * (1.f / 127.f) : 1.f;
  const float inv = (m > 0.f) ? 127.f / m : 1.f;
  uint b[8];
  #pragma unroll
  for (int u = 0; u < 8; ++u) {
    int q[4];
    #pragma unroll
    for (int k = 0; k < 4; ++k)
      q[k] = (int)fminf(fmaxf(rintf(v[u * 4 + k] * inv), -127.f), 127.f);
    b[u] = pack4(q[0], q[1], q[2], q[3]);
  }
  char* dst = Bq + (size_t)o * KTOT + IN_F;
  *(uint4*)(dst)      = uint4{b[0], b[1], b[2], b[3]};
  *(uint4*)(dst + 16) = uint4{b[4], b[5], b[6], b[7]};
  *(uint4*)(dst + 32) = uint4{0, 0, 0, 0};
  *(uint4*)(dst + 48) = uint4{0, 0, 0, 0};
  BsclT[(size_t)64 * OUT_F + o] = ws;
  BsclT[(size_t)65 * OUT_F + o] = 0.f;
}

// ---------------------------------------------------------------------------
// Kernel 7: 256x256 8-phase int8 GEMM with per-group f32 scale-accumulate.
// LDS map (bytes): Abuf b: b*16384 (quarter q at +q*4096, row 64B);
//   Bbuf: 32768 + b*16384; AsclBuf: 65536 + b*1024; BsclBuf: 67584 + b*1024.
// Read swizzle: byte ^= ((row>>1)&3)<<4 (16B chunks within 64B rows).
// K-tile = 64 = one quant group -> exact i32 dot, then acc += as*ws*cvt(d).
// vmcnt(2) at phases 4/8; tail handled by clamped re-stage (group65 scale=0).
// ---------------------------------------------------------------------------
__device__ __forceinline__ void stageA_i8(const char* __restrict__ Atile, char* lds,
                                          int b, int h, int t, int w, int lane)
{
  const int quarter = h + ((w >> 2) << 1);
  const int rq      = ((w & 3) << 4) + (lane >> 2);
  const int schunk  = (lane & 3) ^ ((rq >> 1) & 3);
  const char* src = Atile + (size_t)(quarter * 64 + rq) * KTOT + t * 64 + schunk * 16;
  __builtin_amdgcn_global_load_lds(
      (const __attribute__((address_space(1))) void*)src,
      (__attribute__((address_space(3))) void*)(lds + b * 16384 + quarter * 4096 + ((w & 3) << 10)),
      16, 0, 0);
}

__device__ __forceinline__ void stageB_i8(const char* __restrict__ Btile, char* lds,
                                          int b, int h, int t, int w, int lane)
{
  const int j  = w >> 1;
  const int rr = (h << 5) + ((w & 1) << 4) + (lane >> 2);
  const int schunk = (lane & 3) ^ ((rr >> 1) & 3);
  const char* src = Btile + (size_t)(j * 64 + rr) * KTOT + t * 64 + schunk * 16;
  __builtin_amdgcn_global_load_lds(
      (const __attribute__((address_space(1))) void*)src,
      (__attribute__((address_space(3))) void*)(lds + 32768 + b * 16384 + j * 4096 + (h << 11) + ((w & 1) << 10)),
      16, 0, 0);
}

__device__ __forceinline__ void stageSclA(const float* __restrict__ AsclT, char* lds,
                                          int b, int t, int bm, int lane)
{
  const float* src = AsclT + (size_t)t * NTOK + bm * 256 + lane * 4;
  __builtin_amdgcn_global_load_lds(
      (const __attribute__((address_space(1))) void*)src,
      (__attribute__((address_space(3))) void*)(lds + 65536 + b * 1024), 16, 0, 0);
}

__device__ __forceinline__ void stageSclB(const float* __restrict__ BsclT, char* lds,
                                          int b, int t, int bn, int lane)
{
  const float* src = BsclT + (size_t)t * OUT_F + bn * 256 + lane * 4;
  __builtin_amdgcn_global_load_lds(
      (const __attribute__((address_space(1))) void*)src,
      (__attribute__((address_space(3))) void*)(lds + 67584 + b * 1024), 16, 0, 0);
}

#define PHASE(B_, MQ_, NQ_, STAGE, WAIT2)                                        \
  {                                                                              \
    const int aq = wm * 2 + (MQ_);                                               \
    i32x4 af[4], bfm[2];                                                         \
    f32x4 as4[4];                                                                \
    float wsv[2];                                                                \
    _Pragma("unroll")                                                            \
    for (int mf = 0; mf < 4; ++mf) {                                             \
      const int r = mf * 16 + l15;                                               \
      af[mf] = *(const i32x4*)(lds + (B_) * 16384 + aq * 4096 +                  \
                               ((r * 64 + k16 * 16) ^ (((r >> 1) & 3) << 4)));   \
    }                                                                            \
    _Pragma("unroll")                                                            \
    for (int nf = 0; nf < 2; ++nf) {                                             \
      const int r = (NQ_) * 32 + nf * 16 + l15;                                  \
      bfm[nf] = *(const i32x4*)(lds + 32768 + (B_) * 16384 + wn * 4096 +         \
                                ((r * 64 + k16 * 16) ^ (((r >> 1) & 3) << 4)));  \
    }                                                                            \
    _Pragma("unroll")                                                            \
    for (int mf = 0; mf < 4; ++mf)                                               \
      as4[mf] = *(const f32x4*)(lds + 65536 + (B_) * 1024 +                      \
                                aq * 256 + mf * 64 + (lane >> 4) * 16);          \
    _Pragma("unroll")                                                            \
    for (int nf = 0; nf < 2; ++nf)                                               \
      wsv[nf] = *(const float*)(lds + 67584 + (B_) * 1024 +                      \
                                (wn * 64 + (NQ_) * 32 + nf * 16 + l15) * 4);     \
    STAGE;                                                                       \
    __builtin_amdgcn_s_barrier();                                                \
    __builtin_amdgcn_s_setprio(1);                                               \
    i32x4 d8[4][2];                                                              \
    _Pragma("unroll")                                                            \
    for (int mf = 0; mf < 4; ++mf)                                               \
      _Pragma("unroll")                                                          \
      for (int nf = 0; nf < 2; ++nf)                                             \
        d8[mf][nf] = __builtin_amdgcn_mfma_i32_16x16x64_i8(                      \
            af[mf], bfm[nf], (i32x4){0, 0, 0, 0}, 0, 0, 0);                      \
    _Pragma("unroll")                                                            \
    for (int mf = 0; mf < 4; ++mf)                                               \
      _Pragma("unroll")                                                          \
      for (int nf = 0; nf < 2; ++nf) {                                           \
        f32x4 df;                                                                \
        df[0] = (float)d8[mf][nf][0]; df[1] = (float)d8[mf][nf][1];              \
        df[2] = (float)d8[mf][nf][2]; df[3] = (float)d8[mf][nf][3];              \
        acc[(MQ_) * 4 + mf][(NQ_) * 2 + nf] += as4[mf] * (wsv[nf] * df);         \
      }                                                                          \
    __builtin_amdgcn_s_setprio(0);                                               \
    if (WAIT2) asm volatile("s_waitcnt vmcnt(2)" ::: "memory");                  \
    __builtin_amdgcn_s_barrier();                                                \
  }

__global__ __launch_bounds__(512, 2)
void gemm256_kernel(const char* __restrict__ A, const char* __restrict__ B,
                    const float* __restrict__ AsclT, const float* __restrict__ BsclT,
                    const float* __restrict__ bias, float* __restrict__ C)
{
  extern __shared__ char lds[];
  const int tid = threadIdx.x;
  const int w = tid >> 6, lane = tid & 63;
  const int l15 = lane & 15;
  const int k16 = lane >> 4;
  const int wm = w >> 2, wn = w & 3;          // 2 x 4 waves

  // 2-D XCD chunk swizzle: each XCD owns a 4x8 (bm x bn) region.
  const int xcd = blockIdx.x & 7, idx = blockIdx.x >> 3;
  const int bm = (xcd >> 1) * 4 + (idx >> 3);
  const int bn = (xcd & 1) * 8 + (idx & 7);

  const char* Atile = A + (size_t)bm * 256 * KTOT;
  const char* Btile = B + (size_t)bn * 256 * KTOT;

  f32x4 acc[8][4];
  #pragma unroll
  for (int m = 0; m < 8; ++m)
    #pragma unroll
    for (int n = 0; n < 4; ++n)
      acc[m][n] = f32x4{0.f, 0.f, 0.f, 0.f};

  // Prologue: t0 full (6 loads), t1 half-stages (2). vmcnt(2) -> t0 complete.
  stageA_i8(Atile, lds, 0, 0, 0, w, lane);
  stageB_i8(Btile, lds, 0, 0, 0, w, lane);
  stageSclA(AsclT, lds, 0, 0, bm, lane);
  stageSclB(BsclT, lds, 0, 0, bn, lane);
  stageA_i8(Atile, lds, 0, 1, 0, w, lane);
  stageB_i8(Btile, lds, 0, 1, 0, w, lane);
  stageA_i8(Atile, lds, 1, 0, 1, w, lane);
  stageB_i8(Btile, lds, 1, 0, 1, w, lane);
  asm volatile("s_waitcnt vmcnt(2)" ::: "memory");
  __builtin_amdgcn_s_barrier();

  #pragma unroll 1
  for (int j = 0; j < ITERS; ++j) {
    const int t1 = 2 * j + 1;
    const int t2 = (2 * j + 2 < NKT) ? 2 * j + 2 : NKT - 1;   // clamped re-stage
    const int t3 = (2 * j + 3 < NKT) ? 2 * j + 3 : NKT - 1;   // (group 65: scale 0)
    PHASE(0, 0, 0, { stageB_i8(Btile, lds, 1, 1, t1, w, lane);
                     stageSclA(AsclT, lds, 1, t1, bm, lane); }, 0)
    PHASE(0, 0, 1, { stageA_i8(Atile, lds, 1, 1, t1, w, lane);
                     stageSclB(BsclT, lds, 1, t1, bn, lane); }, 0)
    PHASE(0, 1, 0, { stageA_i8(Atile, lds, 0, 0, t2, w, lane); }, 0)
    PHASE(0, 1, 1, { stageB_i8(Btile, lds, 0, 0, t2, w, lane); }, 1)
    PHASE(1, 0, 0, { stageB_i8(Btile, lds, 0, 1, t2, w, lane);
                     stageSclA(AsclT, lds, 0, t2, bm, lane); }, 0)
    PHASE(1, 0, 1, { stageA_i8(Atile, lds, 0, 1, t2, w, lane);
                     stageSclB(BsclT, lds, 0, t2, bn, lane); }, 0)
    PHASE(1, 1, 0, { stageA_i8(Atile, lds, 1, 0, t3, w, lane); }, 0)
    PHASE(1, 1, 1, { stageB_i8(Btile, lds, 1, 0, t3, w, lane); }, 1)
  }

  // Epilogue: C = acc + bias. Frag: col = l15, row = (lane>>4)*4 + i.
  const int csub = lane >> 4;
  #pragma unroll
  for (int nf = 0; nf < 4; ++nf) {
    const int col = bn * 256 + wn * 64 + nf * 16 + l15;
    const float bv = bias[col];
    #pragma unroll
    for (int mf = 0; mf < 8; ++mf) {
      const int row = bm * 256 + wm * 128 + mf * 16 + csub * 4;
      #pragma unroll
      for (int i = 0; i < 4; ++i)
        C[(size_t)(row + i) * OUT_F + col] = acc[mf][nf][i] + bv;
    }
  }
}

// ---------------------------------------------------------------------------
extern "C" void kernel_launch(void* const* d_in, const int* in_sizes, int n_in,
                              void* d_out, int out_size, void* d_ws, size_t ws_size,
                              hipStream_t stream) {
  const float* x    = (const float*)d_in[0];
  const int*   qw   = (const int*)d_in[1];
  const float* wsc  = (const float*)d_in[2];
  const float* bias = (const float*)d_in[3];
  const float* pd   = (const float*)d_in[4];
  const float* pu   = (const float*)d_in[5];
  float* out = (float*)d_out;

  char*  Aq    = (char*)d_ws;                          // [4096][4224] int8
  char*  Bq    = Aq + (size_t)NTOK * KTOT;             // [4096][4224] int8
  float* AsclT = (float*)(Bq + (size_t)OUT_F * KTOT);  // [66][4096] f32
  float* BsclT = AsclT + (size_t)NKT * NTOK;           // [66][4096] f32
  ushort* pdT  = (ushort*)(BsclT + (size_t)NKT * OUT_F);  // [32][4096] bf16
  float* part  = (float*)(pdT + (size_t)RANK * IN_F);  // [4][4096][32] f32

  hipFuncSetAttribute(reinterpret_cast<const void*>(gemm256_kernel),
                      hipFuncAttributeMaxDynamicSharedMemorySize, 69632);

  quant_kernel<<<16384, 256, 0, stream>>>(x, Aq, AsclT);
  wpack_kernel<<< 4096, 256, 0, stream>>>(qw, wsc, Bq, BsclT);
  pdt_kernel  <<<   16, 256, 0, stream>>>(pd, pdT);
  lrx_kernel  <<<  256, 256, 0, stream>>>(x, pdT, part);
  lrq_kernel  <<<  512, 256, 0, stream>>>(part, Aq, AsclT);
  puq_kernel  <<<   16, 256, 0, stream>>>(pu, Bq, BsclT);
  gemm256_kernel<<<256, 512, 69632, stream>>>(Aq, Bq, AsclT, BsclT, bias, out);
}

// Round 6
// 179.663 us; speedup vs baseline: 1.2636x; 1.2636x over previous
//
#include <hip/hip_runtime.h>
#include <hip/hip_bf16.h>

#define IN_F  4096
#define OUT_F 4096
#define NTOK  4096
#define RANK  32
#define GS    64
#define NG    64
#define KTOT  4224          // 4096 + 32 (low-rank) + 96 zero pad -> 66 * 64
#define NKT   66
#define ITERS 33
#define KCH   1024

typedef __attribute__((ext_vector_type(4))) float f32x4;
typedef __attribute__((ext_vector_type(8))) short bf16x8;

__device__ __forceinline__ ushort f2bf(float f) {
  union { float f; uint u; } c; c.f = f;
  const uint u = c.u;
  return (ushort)((u + 0x7fffu + ((u >> 16) & 1u)) >> 16);  // RNE
}

// ---------------------------------------------------------------------------
// Kernel 1: per-group int8 quant + dequant of x -> A_ext[:, 0:4096] (bf16)
// ---------------------------------------------------------------------------
__global__ __launch_bounds__(256)
void quant_kernel(const float* __restrict__ x, ushort* __restrict__ Aext)
{
  const int tid  = threadIdx.x;
  const int wave = tid >> 6, lane = tid & 63;
  const int sub  = lane & 15;
  const int ggrp = blockIdx.x * 16 + wave * 4 + (lane >> 4);
  const int row  = ggrp >> 6, g = ggrp & 63;

  const float4 v = *(const float4*)(x + (size_t)row * IN_F + g * GS + sub * 4);
  float m = fmaxf(fmaxf(fabsf(v.x), fabsf(v.y)), fmaxf(fabsf(v.z), fabsf(v.w)));
  m = fmaxf(m, __shfl_xor(m, 1));
  m = fmaxf(m, __shfl_xor(m, 2));
  m = fmaxf(m, __shfl_xor(m, 4));
  m = fmaxf(m, __shfl_xor(m, 8));
  const float ascale = (m > 0.f) ? m * (1.f / 127.f) : 1.f;

  const float d0 = fminf(fmaxf(rintf(v.x / ascale), -127.f), 127.f) * ascale;
  const float d1 = fminf(fmaxf(rintf(v.y / ascale), -127.f), 127.f) * ascale;
  const float d2 = fminf(fmaxf(rintf(v.z / ascale), -127.f), 127.f) * ascale;
  const float d3 = fminf(fmaxf(rintf(v.w / ascale), -127.f), 127.f) * ascale;

  uint2 st;
  st.x = (uint)f2bf(d0) | ((uint)f2bf(d1) << 16);
  st.y = (uint)f2bf(d2) | ((uint)f2bf(d3) << 16);
  *(uint2*)(Aext + (size_t)row * KTOT + g * GS + sub * 4) = st;
}

// ---------------------------------------------------------------------------
// Kernel 2: dequant int4 weights -> B_ext[:, 0:4096] (bf16)
// ---------------------------------------------------------------------------
__global__ __launch_bounds__(256)
void wdeq_kernel(const int* __restrict__ qw, const float* __restrict__ wsc,
                 ushort* __restrict__ Bext)
{
  const int gidx = blockIdx.x * 256 + threadIdx.x;
  const int o  = gidx >> 9;
  const int i0 = (gidx & 511) << 3;
  const float sc = wsc[o * NG + (i0 >> 6)];
  const int4 qa = *(const int4*)(qw + (size_t)o * IN_F + i0);
  const int4 qb = *(const int4*)(qw + (size_t)o * IN_F + i0 + 4);
  uint4 st;
  st.x = (uint)f2bf(qa.x * sc) | ((uint)f2bf(qa.y * sc) << 16);
  st.y = (uint)f2bf(qa.z * sc) | ((uint)f2bf(qa.w * sc) << 16);
  st.z = (uint)f2bf(qb.x * sc) | ((uint)f2bf(qb.y * sc) << 16);
  st.w = (uint)f2bf(qb.z * sc) | ((uint)f2bf(qb.w * sc) << 16);
  *(uint4*)(Bext + (size_t)o * KTOT + i0) = st;
}

// ---------------------------------------------------------------------------
// Kernel 3 (aux): pu^T -> B_ext[:, 4096:4128] + zero pad 4128:4224; pd -> pdT.
// ---------------------------------------------------------------------------
__global__ __launch_bounds__(256)
void aux_kernel(const float* __restrict__ pd, const float* __restrict__ pu,
                ushort* __restrict__ Bext, ushort* __restrict__ pdT)
{
  const int id = blockIdx.x * 256 + threadIdx.x;   // 0..4095
  ushort* dst = Bext + (size_t)id * KTOT + IN_F;
  #pragma unroll
  for (int r = 0; r < RANK; ++r) {
    dst[r]            = f2bf(pu[(size_t)r * OUT_F + id]);
    dst[RANK + r]     = 0;
    dst[2 * RANK + r] = 0;
    dst[3 * RANK + r] = 0;
  }
  #pragma unroll
  for (int r = 0; r < RANK; ++r)
    pdT[(size_t)r * IN_F + id] = f2bf(pd[(size_t)id * RANK + r]);
}

// ---------------------------------------------------------------------------
// Kernel 4: lr partials = Aq @ pdT^T via MFMA (64 M-tiles x 4 K-chunks).
// ---------------------------------------------------------------------------
__global__ __launch_bounds__(256)
void lr_kernel(const ushort* __restrict__ A, const ushort* __restrict__ pdT,
               float* __restrict__ part)
{
  __shared__ alignas(16) ushort lA[64 * 64];
  const int tid  = threadIdx.x;
  const int wave = tid >> 6, lane = tid & 63;
  const int mt = blockIdx.x >> 2;
  const int kc = blockIdx.x & 3;
  const int k0 = kc * KCH;

  const int tr  = tid >> 3;
  const int scc = (tid & 7) ^ (tr & 7);
  const ushort* aSrc = A + (size_t)(mt * 64 + tr) * KTOT + k0 + scc * 8;
  char* ldsA = (char*)lA + wave * 1024;

  f32x4 acc[2];
  #pragma unroll
  for (int n = 0; n < 2; ++n) acc[n] = f32x4{0.f, 0.f, 0.f, 0.f};

  for (int kt = 0; kt < KCH / 64; ++kt) {
    const ushort* aS = aSrc + kt * 64;
    #pragma unroll
    for (int j = 0; j < 2; ++j)
      __builtin_amdgcn_global_load_lds(
          (const __attribute__((address_space(1))) void*)(aS + (size_t)j * 32 * KTOT),
          (__attribute__((address_space(3))) void*)(ldsA + j * 4096), 16, 0, 0);
    __syncthreads();
    #pragma unroll
    for (int ks = 0; ks < 2; ++ks) {
      const int kb  = (ks * 32 + (lane >> 4) * 8) * 2;
      const int row = wave * 16 + (lane & 15);
      const int addr = (row * 128 + kb) ^ ((row & 7) << 4);
      bf16x8 af = *(const bf16x8*)((const char*)lA + addr);
      #pragma unroll
      for (int n = 0; n < 2; ++n) {
        const int prow = n * 16 + (lane & 15);
        bf16x8 bf = *(const bf16x8*)(pdT + (size_t)prow * IN_F + k0 + kt * 64 + ks * 32 + (lane >> 4) * 8);
        acc[n] = __builtin_amdgcn_mfma_f32_16x16x32_bf16(af, bf, acc[n], 0, 0, 0);
      }
    }
    __syncthreads();
  }
  const int r0   = lane & 15;
  const int rowb = mt * 64 + wave * 16 + (lane >> 4) * 4;
  #pragma unroll
  for (int n = 0; n < 2; ++n)
    #pragma unroll
    for (int i = 0; i < 4; ++i)
      part[((size_t)kc * 4096 + rowb + i) * 32 + n * 16 + r0] = acc[n][i];
}

// ---------------------------------------------------------------------------
// Kernel 5: combine lr partials -> A_ext[:, 4096:4128], zero 4128:4224.
// ---------------------------------------------------------------------------
__global__ __launch_bounds__(256)
void lrcomb_kernel(const float* __restrict__ part, ushort* __restrict__ Aext)
{
  const int id  = blockIdx.x * 256 + threadIdx.x;
  const int row = id >> 5, r = id & 31;
  const float s = part[(size_t)row * 32 + r]
                + part[(size_t)(4096 + row) * 32 + r]
                + part[(size_t)(8192 + row) * 32 + r]
                + part[(size_t)(12288 + row) * 32 + r];
  ushort* dst = Aext + (size_t)row * KTOT + IN_F;
  dst[r]            = f2bf(s);
  dst[RANK + r]     = 0;
  dst[2 * RANK + r] = 0;
  dst[3 * RANK + r] = 0;
}

// ---------------------------------------------------------------------------
// Kernel 6: 256x256 8-phase GEMM (T2+T3+T4+T5). C = A_ext @ B_ext^T + bias.
// LDS: A buf b at b*32768 (quarter q of 64 rows at +q*8192),
//      B at 65536 + b*32768 (quarter = brow>>6).  XOR swizzle ((r&7)<<4).
// A-half h = quarters {h, h+2}; B-half h = within-quarter rows [h*32,h*32+32).
// R6: minimal read ledger. Phase order per K-tile (MQ,NQ):
//   (0,0)r[A0,B0] -> (0,1)r[B1] -> (1,1)r[A1] -> (1,0)r[none]
// af held across each MQ pair; b0 held P1->P4; b1 held P2->P3.
// Reads/phase: 12,4,8,0 (=24/K-step, minimal). Tail stages clamped to tile 65
// (zeros) so the vmcnt ledger is iteration-invariant (no conditional loads).
// ---------------------------------------------------------------------------
__device__ __forceinline__ void stageA(const ushort* __restrict__ Atile, char* lds,
                                       int b, int h, int kt, int w, int lane)
{
  #pragma unroll
  for (int l = 0; l < 2; ++l) {
    const int g = w * 2 + l;
    const int quarter = h + (g >> 3) * 2;
    const int sub = g & 7;
    const int grow = quarter * 64 + sub * 8 + (lane >> 3);
    const ushort* src = Atile + (size_t)grow * KTOT + kt * 64 + (((lane & 7) ^ (lane >> 3)) << 3);
    __builtin_amdgcn_global_load_lds(
        (const __attribute__((address_space(1))) void*)src,
        (__attribute__((address_space(3))) void*)(lds + b * 32768 + quarter * 8192 + sub * 1024),
        16, 0, 0);
  }
}

__device__ __forceinline__ void stageB(const ushort* __restrict__ Btile, char* lds,
                                       int b, int h, int kt, int w, int lane)
{
  #pragma unroll
  for (int l = 0; l < 2; ++l) {
    const int g = w * 2 + l;
    const int j = g >> 2;
    const int sub = g & 3;
    const int grow = j * 64 + h * 32 + sub * 8 + (lane >> 3);
    const ushort* src = Btile + (size_t)grow * KTOT + kt * 64 + (((lane & 7) ^ (lane >> 3)) << 3);
    __builtin_amdgcn_global_load_lds(
        (const __attribute__((address_space(1))) void*)src,
        (__attribute__((address_space(3))) void*)(lds + 65536 + b * 32768 + j * 8192 + h * 4096 + sub * 1024),
        16, 0, 0);
  }
}

#define PHASE(B_, MQ_, NQ_, READA, READB, BF_, STAGE, WAIT4)                     \
  {                                                                              \
    if (READA) {                                                                 \
      const int aqb = (B_) * 32768 + (wm * 2 + (MQ_)) * 8192;                    \
      _Pragma("unroll")                                                          \
      for (int mf = 0; mf < 4; ++mf) {                                           \
        const int r = mf * 16 + l15;                                             \
        _Pragma("unroll")                                                        \
        for (int ks = 0; ks < 2; ++ks)                                           \
          af[mf][ks] = *(const bf16x8*)(lds + aqb + (((r * 128) + kbyte[ks]) ^ ((r & 7) << 4))); \
      }                                                                          \
    }                                                                            \
    if (READB) {                                                                 \
      const int bqb = 65536 + (B_) * 32768 + wn * 8192;                          \
      _Pragma("unroll")                                                          \
      for (int nf = 0; nf < 2; ++nf) {                                           \
        const int r = ((NQ_) * 2 + nf) * 16 + l15;                               \
        _Pragma("unroll")                                                        \
        for (int ks = 0; ks < 2; ++ks)                                           \
          BF_[nf][ks] = *(const bf16x8*)(lds + bqb + (((r * 128) + kbyte[ks]) ^ ((r & 7) << 4))); \
      }                                                                          \
    }                                                                            \
    STAGE;                                                                       \
    __builtin_amdgcn_s_barrier();                                                \
    __builtin_amdgcn_s_setprio(1);                                               \
    _Pragma("unroll")                                                            \
    for (int mf = 0; mf < 4; ++mf)                                               \
      _Pragma("unroll")                                                          \
      for (int nf = 0; nf < 2; ++nf)                                             \
        _Pragma("unroll")                                                        \
        for (int ks = 0; ks < 2; ++ks)                                           \
          acc[(MQ_) * 4 + mf][(NQ_) * 2 + nf] =                                  \
              __builtin_amdgcn_mfma_f32_16x16x32_bf16(af[mf][ks], BF_[nf][ks],   \
                  acc[(MQ_) * 4 + mf][(NQ_) * 2 + nf], 0, 0, 0);                 \
    __builtin_amdgcn_s_setprio(0);                                               \
    if (WAIT4) asm volatile("s_waitcnt vmcnt(4)" ::: "memory");                  \
    __builtin_amdgcn_s_barrier();                                                \
  }

__global__ __launch_bounds__(512, 2)
void gemm256_kernel(const ushort* __restrict__ A, const ushort* __restrict__ B,
                    const float* __restrict__ bias, float* __restrict__ C)
{
  extern __shared__ char lds[];
  const int tid = threadIdx.x;
  const int w = tid >> 6, lane = tid & 63;
  const int l15 = lane & 15;
  const int wm = w >> 2, wn = w & 3;          // 2 x 4 waves
  int kbyte[2];
  kbyte[0] = ((lane >> 4) * 8) * 2;
  kbyte[1] = (32 + (lane >> 4) * 8) * 2;

  // 2-D XCD chunk swizzle: each XCD owns a 4x8 (bm x bn) region.
  const int xcd = blockIdx.x & 7, idx = blockIdx.x >> 3;
  const int bm = (xcd >> 1) * 4 + (idx >> 3);
  const int bn = (xcd & 1) * 8 + (idx & 7);

  const ushort* Atile = A + (size_t)bm * 256 * KTOT;
  const ushort* Btile = B + (size_t)bn * 256 * KTOT;

  f32x4 acc[8][4];
  #pragma unroll
  for (int m = 0; m < 8; ++m)
    #pragma unroll
    for (int n = 0; n < 4; ++n)
      acc[m][n] = f32x4{0.f, 0.f, 0.f, 0.f};

  // Prologue: buf0 <- tile 0 (all 4 halves), buf1 <- tile 1 (A_H0, B_H0).
  stageA(Atile, lds, 0, 0, 0, w, lane);
  stageB(Btile, lds, 0, 0, 0, w, lane);
  stageB(Btile, lds, 0, 1, 0, w, lane);
  stageA(Atile, lds, 0, 1, 0, w, lane);
  stageA(Atile, lds, 1, 0, 1, w, lane);
  stageB(Btile, lds, 1, 0, 1, w, lane);
  asm volatile("s_waitcnt vmcnt(4)" ::: "memory");
  __builtin_amdgcn_s_barrier();

  #pragma unroll 1
  for (int j = 0; j < ITERS; ++j) {
    const int t1 = 2 * j + 1;
    const int t2 = (2 * j + 2 < NKT) ? 2 * j + 2 : NKT - 1;   // clamped re-stage
    const int t3 = (2 * j + 3 < NKT) ? 2 * j + 3 : NKT - 1;   // (tile 65 = zeros)
    bf16x8 af[4][2], b0[2][2], b1[2][2];
    PHASE(0, 0, 0, 1, 1, b0, { stageB(Btile, lds, 1, 1, t1, w, lane); }, 0)
    PHASE(0, 0, 1, 0, 1, b1, { stageA(Atile, lds, 1, 1, t1, w, lane); }, 0)
    PHASE(0, 1, 1, 1, 0, b1, { stageA(Atile, lds, 0, 0, t2, w, lane); }, 0)
    PHASE(0, 1, 0, 0, 0, b0, { stageB(Btile, lds, 0, 0, t2, w, lane); }, 1)
    PHASE(1, 0, 0, 1, 1, b0, { stageB(Btile, lds, 0, 1, t2, w, lane); }, 0)
    PHASE(1, 0, 1, 0, 1, b1, { stageA(Atile, lds, 0, 1, t2, w, lane); }, 0)
    PHASE(1, 1, 1, 1, 0, b1, { stageA(Atile, lds, 1, 0, t3, w, lane); }, 0)
    PHASE(1, 1, 0, 0, 0, b0, { stageB(Btile, lds, 1, 0, t3, w, lane); }, 1)
  }

  // Epilogue: C = acc + bias. acc frag: col = l15, row = (lane>>4)*4 + i.
  const int csub = lane >> 4;
  #pragma unroll
  for (int nf = 0; nf < 4; ++nf) {
    const int col = bn * 256 + wn * 64 + nf * 16 + l15;
    const float bv = bias[col];
    #pragma unroll
    for (int mf = 0; mf < 8; ++mf) {
      const int row = bm * 256 + wm * 128 + mf * 16 + csub * 4;
      #pragma unroll
      for (int i = 0; i < 4; ++i)
        C[(size_t)(row + i) * OUT_F + col] = acc[mf][nf][i] + bv;
    }
  }
}

// ---------------------------------------------------------------------------
extern "C" void kernel_launch(void* const* d_in, const int* in_sizes, int n_in,
                              void* d_out, int out_size, void* d_ws, size_t ws_size,
                              hipStream_t stream) {
  const float* x    = (const float*)d_in[0];
  const int*   qw   = (const int*)d_in[1];
  const float* wsc  = (const float*)d_in[2];
  const float* bias = (const float*)d_in[3];
  const float* pd   = (const float*)d_in[4];
  const float* pu   = (const float*)d_in[5];
  float* out = (float*)d_out;

  ushort* Aext = (ushort*)d_ws;                        // [4096][4224] bf16
  ushort* Bext = Aext + (size_t)NTOK * KTOT;           // [4096][4224] bf16
  ushort* pdT  = Bext + (size_t)OUT_F * KTOT;          // [32][4096] bf16
  float*  part = (float*)(pdT + (size_t)RANK * IN_F);  // [4][4096][32] f32

  hipFuncSetAttribute(reinterpret_cast<const void*>(gemm256_kernel),
                      hipFuncAttributeMaxDynamicSharedMemorySize, 131072);

  quant_kernel <<<16384, 256, 0, stream>>>(x, Aext);
  wdeq_kernel  <<< 8192, 256, 0, stream>>>(qw, wsc, Bext);
  aux_kernel   <<<   16, 256, 0, stream>>>(pd, pu, Bext, pdT);
  lr_kernel    <<<  256, 256, 0, stream>>>(Aext, pdT, part);
  lrcomb_kernel<<<  512, 256, 0, stream>>>(part, Aext);
  gemm256_kernel<<< 256, 512, 131072, stream>>>(Aext, Bext, bias, out);
}